// Round 5
// baseline (18512.733 us; speedup 1.0000x reference)
//
#include <hip/hip_runtime.h>

// ---------------------------------------------------------------------------
// Net_49976239456390 — 4-layer MLP, boosted k-winner (top-512/8192) + stripe
// top-16/128. Round 5: selection-noise reduction.
//   - GEMM2 (feeds top-k selection) uses fp64 accumulation -> our h2 is the
//     correctly-rounded fp32 of the exact value; rank swaps vs reference now
//     driven only by the reference's own fp32 noise (~sqrt(2)+ fewer swaps).
//   - stripe sums in fp64 + exact 128-way rank (jax leftmost-tie semantics).
//   - GEMM1/3/4 remain fp32 (value-only noise channels, ~1e-6 << threshold).
// Output dtype: fp32 (established in round 4).
// ---------------------------------------------------------------------------

#define BDIM 8192
#define IDIM 4096
#define DDIM 8192
#define XDIM 784
#define KNEUR 512
#define KSTR  16

// identifier-named kernel: grid-stride fp32 fill (sentinel / error codes)
__global__ void Net_49976239456390_kernel(float* out, unsigned long long n, float v)
{
    unsigned long long i = (unsigned long long)blockIdx.x * blockDim.x + threadIdx.x;
    unsigned long long step = (unsigned long long)gridDim.x * blockDim.x;
    for (; i < n; i += step) out[i] = v;
}

// ---- fp32 GEMM: C = relu(A @ B + bias) -------------------------------------
// A:[M,K] B:[K,N] fp32 row-major. BM=BN=128, BK=8, 256 thr, 8x8/thread.
// M%128==0, K%8==0; N guarded (grid.x = ceil(N/128)).
__global__ __launch_bounds__(256)
void gemm_relu(const float* A, const float* B, const float* bias, float* C,
               int N, int K)
{
    __shared__ float as[8][128];
    __shared__ float bs[8][128];

    const int tid = threadIdx.x;
    const int bm = blockIdx.y * 128;
    const int bn = blockIdx.x * 128;
    const int tx = tid & 15, ty = tid >> 4;
    const int r0 = ty * 4, c0 = tx * 4;
    const int a_m = tid >> 1, a_k = (tid & 1) * 4;
    const int b_k = tid >> 5, b_n = (tid & 31) * 4;

    const float* Ap = A + (size_t)(bm + a_m) * K + a_k;
    const float* Bp = B + (size_t)b_k * N + (bn + b_n);
    const bool bok = (bn + b_n + 3 < N);

    float acc[8][8];
#pragma unroll
    for (int i = 0; i < 8; ++i)
#pragma unroll
        for (int j = 0; j < 8; ++j) acc[i][j] = 0.f;

    for (int k0 = 0; k0 < K; k0 += 8) {
        float4 av = *(const float4*)(Ap + k0);
        float4 bv = make_float4(0.f, 0.f, 0.f, 0.f);
        if (bok) bv = *(const float4*)(Bp + (size_t)k0 * N);
        __syncthreads();
        as[a_k + 0][a_m] = av.x;
        as[a_k + 1][a_m] = av.y;
        as[a_k + 2][a_m] = av.z;
        as[a_k + 3][a_m] = av.w;
        *(float4*)&bs[b_k][b_n] = bv;
        __syncthreads();
#pragma unroll
        for (int k = 0; k < 8; ++k) {
            float4 a0 = *(const float4*)&as[k][r0];
            float4 a1 = *(const float4*)&as[k][r0 + 64];
            float4 b0 = *(const float4*)&bs[k][c0];
            float4 b1 = *(const float4*)&bs[k][c0 + 64];
            float aa[8] = {a0.x, a0.y, a0.z, a0.w, a1.x, a1.y, a1.z, a1.w};
            float bb[8] = {b0.x, b0.y, b0.z, b0.w, b1.x, b1.y, b1.z, b1.w};
#pragma unroll
            for (int i = 0; i < 8; ++i)
#pragma unroll
                for (int j = 0; j < 8; ++j)
                    acc[i][j] = fmaf(aa[i], bb[j], acc[i][j]);
        }
    }

#pragma unroll
    for (int i = 0; i < 8; ++i) {
        const int rr = bm + r0 + ((i >> 2) << 6) + (i & 3);
        float* op = C + (size_t)rr * N;
#pragma unroll
        for (int j = 0; j < 8; ++j) {
            int cc = bn + c0 + ((j >> 2) << 6) + (j & 3);
            if (cc < N)
                op[cc] = fmaxf(acc[i][j] + bias[cc], 0.f);
        }
    }
}

// ---- fp64-accumulate GEMM: C = relu(A @ B + bias), fp32 in/out -------------
// Products fp32xfp32 are EXACT in fp64; accumulation order-independent to
// 2^-53 -> stored C = correctly-rounded fp32 of the true value.
// BM=BN=64, BK=16, 256 thr, 4x4 doubles/thread. M%64==0, N%64==0, K%16==0.
__global__ __launch_bounds__(256)
void gemm_relu_f64(const float* A, const float* B, const float* bias, float* C,
                   int N, int K)
{
    __shared__ float as[16][64];
    __shared__ float bs[16][64];

    const int tid = threadIdx.x;
    const int bm = blockIdx.y * 64;
    const int bn = blockIdx.x * 64;
    const int ty = tid >> 4, tx = tid & 15;
    const int r0 = ty * 4, c0 = tx * 4;
    const int a_m = tid >> 2, a_k = (tid & 3) * 4;   // 64 rows x 16 k
    const int b_k = tid >> 4, b_n = (tid & 15) * 4;  // 16 k x 64 n

    const float* Ap = A + (size_t)(bm + a_m) * K + a_k;
    const float* Bp = B + (size_t)b_k * N + (bn + b_n);

    double acc[4][4];
#pragma unroll
    for (int i = 0; i < 4; ++i)
#pragma unroll
        for (int j = 0; j < 4; ++j) acc[i][j] = 0.0;

    for (int k0 = 0; k0 < K; k0 += 16) {
        float4 av = *(const float4*)(Ap + k0);
        float4 bv = *(const float4*)(Bp + (size_t)k0 * N);
        __syncthreads();
        as[a_k + 0][a_m] = av.x;
        as[a_k + 1][a_m] = av.y;
        as[a_k + 2][a_m] = av.z;
        as[a_k + 3][a_m] = av.w;
        *(float4*)&bs[b_k][b_n] = bv;
        __syncthreads();
#pragma unroll
        for (int k = 0; k < 16; ++k) {
            float4 a4 = *(const float4*)&as[k][r0];
            float4 b4 = *(const float4*)&bs[k][c0];
            double aa[4] = {a4.x, a4.y, a4.z, a4.w};
            double bb[4] = {b4.x, b4.y, b4.z, b4.w};
#pragma unroll
            for (int i = 0; i < 4; ++i)
#pragma unroll
                for (int j = 0; j < 4; ++j)
                    acc[i][j] = fma(aa[i], bb[j], acc[i][j]);
        }
    }

#pragma unroll
    for (int i = 0; i < 4; ++i) {
        float* op = C + (size_t)(bm + r0 + i) * N + bn;
#pragma unroll
        for (int j = 0; j < 4; ++j)
            op[c0 + j] = fmaxf((float)acc[i][j] + bias[bn + c0 + j], 0.f);
    }
}

// ---- k-winner (exact top-512, radix on fp32 bits, jax leftmost ties) ------
// + stripe top-16 via fp64 sums and exact 128-way rank. In place on h2 row.
__global__ __launch_bounds__(256)
void kwinner_stripes(float* h2, const float* bscores)
{
    const int row = blockIdx.x;
    const int tid = threadIdx.x;
    float* rowp = h2 + (size_t)row * DDIM;

    __shared__ float  mv[DDIM];      // 32 KB
    __shared__ int    ired[256];
    __shared__ double dred[256];
    __shared__ int    warr[4];
    __shared__ double ssum[128];
    __shared__ float  smk[128];

#pragma unroll
    for (int i = 0; i < 32; ++i) {
        int j = tid + i * 256;
        mv[j] = expf(0.0f - bscores[j]) * rowp[j];   // BETA=1, GAMMA=0
    }
    __syncthreads();

    // radix-descend: t = fp32 bit pattern of the 512th-largest m (all m >= +0)
    unsigned t = 0;
    for (int bit = 30; bit >= 0; --bit) {
        unsigned cand = t | (1u << bit);
        int cnt = 0;
#pragma unroll
        for (int i = 0; i < 32; ++i)
            cnt += (__float_as_uint(mv[tid + i * 256]) >= cand) ? 1 : 0;
        for (int off = 32; off; off >>= 1) cnt += __shfl_down(cnt, off);
        if ((tid & 63) == 0) warr[tid >> 6] = cnt;
        __syncthreads();
        int tot = warr[0] + warr[1] + warr[2] + warr[3];
        __syncthreads();
        if (tot >= KNEUR) t = cand;
    }
    {   // count strictly greater than t
        int cnt = 0;
#pragma unroll
        for (int i = 0; i < 32; ++i)
            cnt += (__float_as_uint(mv[tid + i * 256]) > t) ? 1 : 0;
        for (int off = 32; off; off >>= 1) cnt += __shfl_down(cnt, off);
        if ((tid & 63) == 0) warr[tid >> 6] = cnt;
        __syncthreads();
    }
    const int need_eq = KNEUR - (warr[0] + warr[1] + warr[2] + warr[3]);
    __syncthreads();

    // leftmost tie-break: exclusive prefix of (==t) counts over 32-chunks
    const int base = tid * 32;
    int myeq = 0;
#pragma unroll
    for (int i = 0; i < 32; ++i)
        myeq += (__float_as_uint(mv[base + i]) == t) ? 1 : 0;
    int val = myeq;
    ired[tid] = val;
    __syncthreads();
    for (int s = 1; s < 256; s <<= 1) {
        int add = (tid >= s) ? ired[tid - s] : 0;
        __syncthreads();
        val += add;
        ired[tid] = val;
        __syncthreads();
    }
    const int before = val - myeq;

    // select, code = m*h2 (fp32, bit-faithful), fp64 partial sums
    double partial = 0.0;
    int eqseen = 0;
#pragma unroll
    for (int i = 0; i < 32; ++i) {
        int j = base + i;
        float m = mv[j];
        unsigned u = __float_as_uint(m);
        bool sel = (u > t) || (u == t && (before + eqseen) < need_eq);
        if (u == t) ++eqseen;
        float code = sel ? m * rowp[j] : 0.f;
        mv[j] = code;
        partial += (double)code;
    }
    dred[tid] = partial;
    __syncthreads();
    if (tid < 128) ssum[tid] = dred[2 * tid] + dred[2 * tid + 1]; // stripe sum
    __syncthreads();

    // exact stripe top-16: rank = #greater + #equal-at-lower-index
    if (tid < 128) {
        double v = ssum[tid];
        int rank = 0;
        for (int j = 0; j < 128; ++j) {
            double w = ssum[j];
            rank += (w > v) ? 1 : 0;
            rank += (w == v && j < tid) ? 1 : 0;
        }
        smk[tid] = (rank < KSTR) ? 1.f : 0.f;
    }
    __syncthreads();

#pragma unroll
    for (int i = 0; i < 32; ++i) {
        int j = tid + i * 256;
        rowp[j] = mv[j] * smk[j >> 6];
    }
}

extern "C" void kernel_launch(void* const* d_in, const int* in_sizes, int n_in,
                              void* d_out, int out_size, void* d_ws, size_t ws_size,
                              hipStream_t stream)
{
    float* out = (float*)d_out;
    const unsigned long long on = (unsigned long long)out_size;

    if (n_in != 10) {
        Net_49976239456390_kernel<<<1024, 256, 0, stream>>>(out, on, 55.f);
        return;
    }
    if (in_sizes[0] != BDIM * XDIM || in_sizes[3] != IDIM * DDIM || in_sizes[9] != DDIM) {
        Net_49976239456390_kernel<<<1024, 256, 0, stream>>>(out, on, 66.f);
        return;
    }

    const size_t per_row = (size_t)(IDIM + DDIM) * 4;
    int R = 0;
    for (int cand = BDIM; cand >= 128; cand >>= 1)
        if ((size_t)cand * per_row <= ws_size) { R = cand; break; }
    if (R == 0) {
        Net_49976239456390_kernel<<<1024, 256, 0, stream>>>(out, on, 99.f);
        return;
    }

    Net_49976239456390_kernel<<<1024, 256, 0, stream>>>(out, on, 7.f);

    const float* x   = (const float*)d_in[0];
    const float* W1  = (const float*)d_in[1];
    const float* b1  = (const float*)d_in[2];
    const float* W2  = (const float*)d_in[3];
    const float* b2  = (const float*)d_in[4];
    const float* W3  = (const float*)d_in[5];
    const float* b3  = (const float*)d_in[6];
    const float* W4  = (const float*)d_in[7];
    const float* b4  = (const float*)d_in[8];
    const float* bsc = (const float*)d_in[9];

    float* h1 = (float*)d_ws;
    float* h2 = h1 + (size_t)R * IDIM;

    dim3 blk(256);
    for (int cs = 0; cs < BDIM; cs += R) {
        const float* xC = x + (size_t)cs * XDIM;
        float* outC = out + (size_t)cs * XDIM;

        gemm_relu<<<dim3(IDIM / 128, R / 128), blk, 0, stream>>>(xC, W1, b1, h1, IDIM, XDIM);
        gemm_relu_f64<<<dim3(DDIM / 64, R / 64), blk, 0, stream>>>(h1, W2, b2, h2, DDIM, IDIM);
        kwinner_stripes<<<dim3(R), blk, 0, stream>>>(h2, bsc);
        gemm_relu<<<dim3(IDIM / 128, R / 128), blk, 0, stream>>>(h2, W3, b3, h1, IDIM, DDIM);
        gemm_relu<<<dim3((XDIM + 127) / 128, R / 128), blk, 0, stream>>>(h1, W4, b4, outC, XDIM, IDIM);
    }
}

// Round 6
// 10039.526 us; speedup vs baseline: 1.8440x; 1.8440x over previous
//
#include <hip/hip_runtime.h>
#include <hip/hip_bf16.h>

// ---------------------------------------------------------------------------
// Net_49976239456390 — 4-layer MLP, boosted k-winner (top-512/8192) + stripe
// top-16/128. Round 6: GEMM2 (selection-critical, was fp64 @13.8ms) replaced
// by 3-term bf16-split MFMA GEMM (6 products, i+j<=2, dual accumulators).
//   - exact split: f32 = b0+b1+b2 (bf16 each), residuals exact in f32
//   - error ~5e-7 rel << reference fp32 noise -> selection swaps unchanged
//   - splits computed in-kernel during staging (no extra workspace)
// Everything else identical to the passing round-5 kernel.
// ---------------------------------------------------------------------------

#define BDIM 8192
#define IDIM 4096
#define DDIM 8192
#define XDIM 784
#define KNEUR 512
#define KSTR  16

typedef __attribute__((ext_vector_type(8))) short bf16x8;
typedef __attribute__((ext_vector_type(4))) float f32x4;

#define LDT 40   // padded LDS row length in bf16 elems (80 B, 16B-aligned)

// identifier-named kernel: grid-stride fp32 fill (sentinel / error codes)
__global__ void Net_49976239456390_kernel(float* out, unsigned long long n, float v)
{
    unsigned long long i = (unsigned long long)blockIdx.x * blockDim.x + threadIdx.x;
    unsigned long long step = (unsigned long long)gridDim.x * blockDim.x;
    for (; i < n; i += step) out[i] = v;
}

// ---- fp32 GEMM: C = relu(A @ B + bias) (GEMM1/3/4) --------------------------
__global__ __launch_bounds__(256)
void gemm_relu(const float* A, const float* B, const float* bias, float* C,
               int N, int K)
{
    __shared__ float as[8][128];
    __shared__ float bs[8][128];

    const int tid = threadIdx.x;
    const int bm = blockIdx.y * 128;
    const int bn = blockIdx.x * 128;
    const int tx = tid & 15, ty = tid >> 4;
    const int r0 = ty * 4, c0 = tx * 4;
    const int a_m = tid >> 1, a_k = (tid & 1) * 4;
    const int b_k = tid >> 5, b_n = (tid & 31) * 4;

    const float* Ap = A + (size_t)(bm + a_m) * K + a_k;
    const float* Bp = B + (size_t)b_k * N + (bn + b_n);
    const bool bok = (bn + b_n + 3 < N);

    float acc[8][8];
#pragma unroll
    for (int i = 0; i < 8; ++i)
#pragma unroll
        for (int j = 0; j < 8; ++j) acc[i][j] = 0.f;

    for (int k0 = 0; k0 < K; k0 += 8) {
        float4 av = *(const float4*)(Ap + k0);
        float4 bv = make_float4(0.f, 0.f, 0.f, 0.f);
        if (bok) bv = *(const float4*)(Bp + (size_t)k0 * N);
        __syncthreads();
        as[a_k + 0][a_m] = av.x;
        as[a_k + 1][a_m] = av.y;
        as[a_k + 2][a_m] = av.z;
        as[a_k + 3][a_m] = av.w;
        *(float4*)&bs[b_k][b_n] = bv;
        __syncthreads();
#pragma unroll
        for (int k = 0; k < 8; ++k) {
            float4 a0 = *(const float4*)&as[k][r0];
            float4 a1 = *(const float4*)&as[k][r0 + 64];
            float4 b0 = *(const float4*)&bs[k][c0];
            float4 b1 = *(const float4*)&bs[k][c0 + 64];
            float aa[8] = {a0.x, a0.y, a0.z, a0.w, a1.x, a1.y, a1.z, a1.w};
            float bb[8] = {b0.x, b0.y, b0.z, b0.w, b1.x, b1.y, b1.z, b1.w};
#pragma unroll
            for (int i = 0; i < 8; ++i)
#pragma unroll
                for (int j = 0; j < 8; ++j)
                    acc[i][j] = fmaf(aa[i], bb[j], acc[i][j]);
        }
    }

#pragma unroll
    for (int i = 0; i < 8; ++i) {
        const int rr = bm + r0 + ((i >> 2) << 6) + (i & 3);
        float* op = C + (size_t)rr * N;
#pragma unroll
        for (int j = 0; j < 8; ++j) {
            int cc = bn + c0 + ((j >> 2) << 6) + (j & 3);
            if (cc < N)
                op[cc] = fmaxf(acc[i][j] + bias[cc], 0.f);
        }
    }
}

// ---- exact 3-term bf16 split ------------------------------------------------
__device__ __forceinline__ void split3(float f, short& s0, short& s1, short& s2)
{
    __hip_bfloat16 b0 = __float2bfloat16(f);
    float r1 = f - __bfloat162float(b0);
    __hip_bfloat16 b1 = __float2bfloat16(r1);
    float r2 = r1 - __bfloat162float(b1);
    __hip_bfloat16 b2 = __float2bfloat16(r2);
    s0 = *(short*)&b0; s1 = *(short*)&b1; s2 = *(short*)&b2;
}

// ---- GEMM2: C = relu(A @ B + bias) via bf16-split MFMA ----------------------
// A: h1 [M][IDIM] fp32, B: W2 [IDIM][DDIM] fp32, C: h2 [M][DDIM] fp32.
// 128x128 tile, BK=32, 256 thr (4 waves, 2x2 of 64x64), 16x16x32 bf16 MFMA.
// 6 products (i+j<=2); a0*b0 -> accM, rest -> accR (dual-accumulator).
__global__ __launch_bounds__(256, 2)
void gemm2_split(const float* __restrict__ A, const float* __restrict__ B,
                 const float* __restrict__ bias, float* __restrict__ C)
{
    __shared__ short as[3][128 * LDT];   // 30720 B
    __shared__ short bs[3][128 * LDT];   // 30720 B
    __shared__ float bsrc[32 * 128];     // 16384 B

    const int tid = threadIdx.x;
    const int lane = tid & 63;
    const int wid = tid >> 6;
    const int wr = (wid >> 1) * 64;      // wave row offset in tile
    const int wc = (wid & 1) * 64;       // wave col offset
    const int l15 = lane & 15;
    const int lk8 = (lane >> 4) * 8;     // k-offset of this lane's frag
    const int bm = blockIdx.y * 128;
    const int bn = blockIdx.x * 128;

    const int tn = tid & 127;            // transpose task: col
    const int tkh = (tid >> 7) * 16;     // transpose task: k half

    f32x4 accM[4][4];
    f32x4 accR[4][4];
#pragma unroll
    for (int i = 0; i < 4; ++i)
#pragma unroll
        for (int j = 0; j < 4; ++j) {
            accM[i][j] = (f32x4){0.f, 0.f, 0.f, 0.f};
            accR[i][j] = (f32x4){0.f, 0.f, 0.f, 0.f};
        }

    for (int k0 = 0; k0 < IDIM; k0 += 32) {
        __syncthreads();   // prior iteration's frag reads + bsrc reads done

        // stage A: 128m x 32k fp32 -> split -> as[0..2]
#pragma unroll
        for (int pass = 0; pass < 4; ++pass) {
            int idx = pass * 256 + tid;
            int m = idx >> 3;
            int kf = (idx & 7) << 2;
            float4 v = *(const float4*)(A + (size_t)(bm + m) * IDIM + k0 + kf);
            short s0[4], s1[4], s2[4];
            split3(v.x, s0[0], s1[0], s2[0]);
            split3(v.y, s0[1], s1[1], s2[1]);
            split3(v.z, s0[2], s1[2], s2[2]);
            split3(v.w, s0[3], s1[3], s2[3]);
            int off = m * LDT + kf;
            *(short4*)&as[0][off] = make_short4(s0[0], s0[1], s0[2], s0[3]);
            *(short4*)&as[1][off] = make_short4(s1[0], s1[1], s1[2], s1[3]);
            *(short4*)&as[2][off] = make_short4(s2[0], s2[1], s2[2], s2[3]);
        }
        // stage B pass 1: 32k x 128n fp32, coalesced -> bsrc
#pragma unroll
        for (int pass = 0; pass < 4; ++pass) {
            int idx = pass * 256 + tid;
            int k = idx >> 5;
            int nf = (idx & 31) << 2;
            float4 v = *(const float4*)(B + (size_t)(k0 + k) * DDIM + bn + nf);
            *(float4*)&bsrc[k * 128 + nf] = v;
        }
        __syncthreads();   // bsrc ready

        // stage B pass 2: transpose + split -> bs[0..2] rows = cols of B
#pragma unroll
        for (int q = 0; q < 4; ++q) {
            int kq = tkh + q * 4;
            short s0[4], s1[4], s2[4];
#pragma unroll
            for (int e = 0; e < 4; ++e) {
                float f = bsrc[(kq + e) * 128 + tn];
                split3(f, s0[e], s1[e], s2[e]);
            }
            int off = tn * LDT + kq;
            *(short4*)&bs[0][off] = make_short4(s0[0], s0[1], s0[2], s0[3]);
            *(short4*)&bs[1][off] = make_short4(s1[0], s1[1], s1[2], s1[3]);
            *(short4*)&bs[2][off] = make_short4(s2[0], s2[1], s2[2], s2[3]);
        }
        __syncthreads();   // tiles ready

        // load all a-frags (3 splits x 4 m-frags)
        bf16x8 af[3][4];
#pragma unroll
        for (int p = 0; p < 3; ++p)
#pragma unroll
            for (int mi = 0; mi < 4; ++mi)
                af[p][mi] = *(const bf16x8*)&as[p][(wr + mi * 16 + l15) * LDT + lk8];

        // 6 products: q=0: p=0,1,2; q=1: p=0,1; q=2: p=0
#pragma unroll
        for (int q = 0; q < 3; ++q) {
            bf16x8 bf[4];
#pragma unroll
            for (int ni = 0; ni < 4; ++ni)
                bf[ni] = *(const bf16x8*)&bs[q][(wc + ni * 16 + l15) * LDT + lk8];
#pragma unroll
            for (int p = 0; p < 3; ++p) {
                if (p + q > 2) continue;
                if (p == 0 && q == 0) {
#pragma unroll
                    for (int mi = 0; mi < 4; ++mi)
#pragma unroll
                        for (int ni = 0; ni < 4; ++ni)
                            accM[mi][ni] = __builtin_amdgcn_mfma_f32_16x16x32_bf16(
                                af[0][mi], bf[ni], accM[mi][ni], 0, 0, 0);
                } else {
#pragma unroll
                    for (int mi = 0; mi < 4; ++mi)
#pragma unroll
                        for (int ni = 0; ni < 4; ++ni)
                            accR[mi][ni] = __builtin_amdgcn_mfma_f32_16x16x32_bf16(
                                af[p][mi], bf[ni], accR[mi][ni], 0, 0, 0);
                }
            }
        }
    }

    // epilogue: C[row][col] = relu((accR+accM) + bias)
    const int rsub = (lane >> 4) * 4;
#pragma unroll
    for (int mi = 0; mi < 4; ++mi) {
        int row0 = bm + wr + mi * 16 + rsub;
#pragma unroll
        for (int ni = 0; ni < 4; ++ni) {
            int col = bn + wc + ni * 16 + l15;
            float bb = bias[col];
#pragma unroll
            for (int r = 0; r < 4; ++r) {
                float s = accR[mi][ni][r] + accM[mi][ni][r];
                C[(size_t)(row0 + r) * DDIM + col] = fmaxf(s + bb, 0.f);
            }
        }
    }
}

// ---- k-winner (exact top-512, radix on fp32 bits, jax leftmost ties) -------
__global__ __launch_bounds__(256)
void kwinner_stripes(float* h2, const float* bscores)
{
    const int row = blockIdx.x;
    const int tid = threadIdx.x;
    float* rowp = h2 + (size_t)row * DDIM;

    __shared__ float  mv[DDIM];
    __shared__ int    ired[256];
    __shared__ double dred[256];
    __shared__ int    warr[4];
    __shared__ double ssum[128];
    __shared__ float  smk[128];

#pragma unroll
    for (int i = 0; i < 32; ++i) {
        int j = tid + i * 256;
        mv[j] = expf(0.0f - bscores[j]) * rowp[j];   // BETA=1, GAMMA=0
    }
    __syncthreads();

    unsigned t = 0;
    for (int bit = 30; bit >= 0; --bit) {
        unsigned cand = t | (1u << bit);
        int cnt = 0;
#pragma unroll
        for (int i = 0; i < 32; ++i)
            cnt += (__float_as_uint(mv[tid + i * 256]) >= cand) ? 1 : 0;
        for (int off = 32; off; off >>= 1) cnt += __shfl_down(cnt, off);
        if ((tid & 63) == 0) warr[tid >> 6] = cnt;
        __syncthreads();
        int tot = warr[0] + warr[1] + warr[2] + warr[3];
        __syncthreads();
        if (tot >= KNEUR) t = cand;
    }
    {
        int cnt = 0;
#pragma unroll
        for (int i = 0; i < 32; ++i)
            cnt += (__float_as_uint(mv[tid + i * 256]) > t) ? 1 : 0;
        for (int off = 32; off; off >>= 1) cnt += __shfl_down(cnt, off);
        if ((tid & 63) == 0) warr[tid >> 6] = cnt;
        __syncthreads();
    }
    const int need_eq = KNEUR - (warr[0] + warr[1] + warr[2] + warr[3]);
    __syncthreads();

    const int base = tid * 32;
    int myeq = 0;
#pragma unroll
    for (int i = 0; i < 32; ++i)
        myeq += (__float_as_uint(mv[base + i]) == t) ? 1 : 0;
    int val = myeq;
    ired[tid] = val;
    __syncthreads();
    for (int s = 1; s < 256; s <<= 1) {
        int add = (tid >= s) ? ired[tid - s] : 0;
        __syncthreads();
        val += add;
        ired[tid] = val;
        __syncthreads();
    }
    const int before = val - myeq;

    double partial = 0.0;
    int eqseen = 0;
#pragma unroll
    for (int i = 0; i < 32; ++i) {
        int j = base + i;
        float m = mv[j];
        unsigned u = __float_as_uint(m);
        bool sel = (u > t) || (u == t && (before + eqseen) < need_eq);
        if (u == t) ++eqseen;
        float code = sel ? m * rowp[j] : 0.f;
        mv[j] = code;
        partial += (double)code;
    }
    dred[tid] = partial;
    __syncthreads();
    if (tid < 128) ssum[tid] = dred[2 * tid] + dred[2 * tid + 1];
    __syncthreads();

    if (tid < 128) {
        double v = ssum[tid];
        int rank = 0;
        for (int j = 0; j < 128; ++j) {
            double w = ssum[j];
            rank += (w > v) ? 1 : 0;
            rank += (w == v && j < tid) ? 1 : 0;
        }
        smk[tid] = (rank < KSTR) ? 1.f : 0.f;
    }
    __syncthreads();

#pragma unroll
    for (int i = 0; i < 32; ++i) {
        int j = tid + i * 256;
        rowp[j] = mv[j] * smk[j >> 6];
    }
}

extern "C" void kernel_launch(void* const* d_in, const int* in_sizes, int n_in,
                              void* d_out, int out_size, void* d_ws, size_t ws_size,
                              hipStream_t stream)
{
    float* out = (float*)d_out;
    const unsigned long long on = (unsigned long long)out_size;

    if (n_in != 10) {
        Net_49976239456390_kernel<<<1024, 256, 0, stream>>>(out, on, 55.f);
        return;
    }
    if (in_sizes[0] != BDIM * XDIM || in_sizes[3] != IDIM * DDIM || in_sizes[9] != DDIM) {
        Net_49976239456390_kernel<<<1024, 256, 0, stream>>>(out, on, 66.f);
        return;
    }

    const size_t per_row = (size_t)(IDIM + DDIM) * 4;
    int R = 0;
    for (int cand = BDIM; cand >= 128; cand >>= 1)
        if ((size_t)cand * per_row <= ws_size) { R = cand; break; }
    if (R == 0) {
        Net_49976239456390_kernel<<<1024, 256, 0, stream>>>(out, on, 99.f);
        return;
    }

    Net_49976239456390_kernel<<<1024, 256, 0, stream>>>(out, on, 7.f);

    const float* x   = (const float*)d_in[0];
    const float* W1  = (const float*)d_in[1];
    const float* b1  = (const float*)d_in[2];
    const float* W2  = (const float*)d_in[3];
    const float* b2  = (const float*)d_in[4];
    const float* W3  = (const float*)d_in[5];
    const float* b3  = (const float*)d_in[6];
    const float* W4  = (const float*)d_in[7];
    const float* b4  = (const float*)d_in[8];
    const float* bsc = (const float*)d_in[9];

    float* h1 = (float*)d_ws;
    float* h2 = h1 + (size_t)R * IDIM;

    dim3 blk(256);
    for (int cs = 0; cs < BDIM; cs += R) {
        const float* xC = x + (size_t)cs * XDIM;
        float* outC = out + (size_t)cs * XDIM;

        gemm_relu<<<dim3(IDIM / 128, R / 128), blk, 0, stream>>>(xC, W1, b1, h1, IDIM, XDIM);
        gemm2_split<<<dim3(DDIM / 128, R / 128), blk, 0, stream>>>(h1, W2, b2, h2);
        kwinner_stripes<<<dim3(R), blk, 0, stream>>>(h2, bsc);
        gemm_relu<<<dim3(IDIM / 128, R / 128), blk, 0, stream>>>(h2, W3, b3, h1, IDIM, DDIM);
        gemm_relu<<<dim3((XDIM + 127) / 128, R / 128), blk, 0, stream>>>(h1, W4, b4, outC, XDIM, IDIM);
    }
}

// Round 7
// 6829.228 us; speedup vs baseline: 2.7108x; 1.4701x over previous
//
#include <hip/hip_runtime.h>
#include <hip/hip_bf16.h>

// ---------------------------------------------------------------------------
// Net_49976239456390 — 4-layer MLP, boosted k-winner (top-512/8192) + stripe
// top-16/128. Round 7: GEMM3 (value-only, was fp32 @5.8ms) -> 2-term
// bf16-split MFMA (3 products: a0b0 + a0b1 + a1b0; dropped a1b1 ~2^-16 rel).
// GEMM2 keeps the selection-safe 3-term/6-product split from round 6.
// ---------------------------------------------------------------------------

#define BDIM 8192
#define IDIM 4096
#define DDIM 8192
#define XDIM 784
#define KNEUR 512
#define KSTR  16

typedef __attribute__((ext_vector_type(8))) short bf16x8;
typedef __attribute__((ext_vector_type(4))) float f32x4;

#define LDT 40   // padded LDS row length in bf16 elems (80 B, 16B-aligned)

// identifier-named kernel: grid-stride fp32 fill (sentinel / error codes)
__global__ void Net_49976239456390_kernel(float* out, unsigned long long n, float v)
{
    unsigned long long i = (unsigned long long)blockIdx.x * blockDim.x + threadIdx.x;
    unsigned long long step = (unsigned long long)gridDim.x * blockDim.x;
    for (; i < n; i += step) out[i] = v;
}

// ---- fp32 GEMM: C = relu(A @ B + bias) (GEMM1/4) ----------------------------
__global__ __launch_bounds__(256)
void gemm_relu(const float* A, const float* B, const float* bias, float* C,
               int N, int K)
{
    __shared__ float as[8][128];
    __shared__ float bs[8][128];

    const int tid = threadIdx.x;
    const int bm = blockIdx.y * 128;
    const int bn = blockIdx.x * 128;
    const int tx = tid & 15, ty = tid >> 4;
    const int r0 = ty * 4, c0 = tx * 4;
    const int a_m = tid >> 1, a_k = (tid & 1) * 4;
    const int b_k = tid >> 5, b_n = (tid & 31) * 4;

    const float* Ap = A + (size_t)(bm + a_m) * K + a_k;
    const float* Bp = B + (size_t)b_k * N + (bn + b_n);
    const bool bok = (bn + b_n + 3 < N);

    float acc[8][8];
#pragma unroll
    for (int i = 0; i < 8; ++i)
#pragma unroll
        for (int j = 0; j < 8; ++j) acc[i][j] = 0.f;

    for (int k0 = 0; k0 < K; k0 += 8) {
        float4 av = *(const float4*)(Ap + k0);
        float4 bv = make_float4(0.f, 0.f, 0.f, 0.f);
        if (bok) bv = *(const float4*)(Bp + (size_t)k0 * N);
        __syncthreads();
        as[a_k + 0][a_m] = av.x;
        as[a_k + 1][a_m] = av.y;
        as[a_k + 2][a_m] = av.z;
        as[a_k + 3][a_m] = av.w;
        *(float4*)&bs[b_k][b_n] = bv;
        __syncthreads();
#pragma unroll
        for (int k = 0; k < 8; ++k) {
            float4 a0 = *(const float4*)&as[k][r0];
            float4 a1 = *(const float4*)&as[k][r0 + 64];
            float4 b0 = *(const float4*)&bs[k][c0];
            float4 b1 = *(const float4*)&bs[k][c0 + 64];
            float aa[8] = {a0.x, a0.y, a0.z, a0.w, a1.x, a1.y, a1.z, a1.w};
            float bb[8] = {b0.x, b0.y, b0.z, b0.w, b1.x, b1.y, b1.z, b1.w};
#pragma unroll
            for (int i = 0; i < 8; ++i)
#pragma unroll
                for (int j = 0; j < 8; ++j)
                    acc[i][j] = fmaf(aa[i], bb[j], acc[i][j]);
        }
    }

#pragma unroll
    for (int i = 0; i < 8; ++i) {
        const int rr = bm + r0 + ((i >> 2) << 6) + (i & 3);
        float* op = C + (size_t)rr * N;
#pragma unroll
        for (int j = 0; j < 8; ++j) {
            int cc = bn + c0 + ((j >> 2) << 6) + (j & 3);
            if (cc < N)
                op[cc] = fmaxf(acc[i][j] + bias[cc], 0.f);
        }
    }
}

// ---- exact bf16 splits ------------------------------------------------------
__device__ __forceinline__ void split3(float f, short& s0, short& s1, short& s2)
{
    __hip_bfloat16 b0 = __float2bfloat16(f);
    float r1 = f - __bfloat162float(b0);
    __hip_bfloat16 b1 = __float2bfloat16(r1);
    float r2 = r1 - __bfloat162float(b1);
    __hip_bfloat16 b2 = __float2bfloat16(r2);
    s0 = *(short*)&b0; s1 = *(short*)&b1; s2 = *(short*)&b2;
}

__device__ __forceinline__ void split2(float f, short& s0, short& s1)
{
    __hip_bfloat16 b0 = __float2bfloat16(f);
    float r1 = f - __bfloat162float(b0);
    __hip_bfloat16 b1 = __float2bfloat16(r1);
    s0 = *(short*)&b0; s1 = *(short*)&b1;
}

// ---- GEMM2: h2 = relu(h1 @ W2 + b2), 3-term split (selection-critical) -----
// A: [M][IDIM] fp32, B: [IDIM][DDIM] fp32, C: [M][DDIM] fp32.
// 128x128 tile, BK=32, 256 thr (2x2 waves of 64x64), 16x16x32 bf16 MFMA.
__global__ __launch_bounds__(256, 2)
void gemm2_split(const float* __restrict__ A, const float* __restrict__ B,
                 const float* __restrict__ bias, float* __restrict__ C)
{
    __shared__ short as[3][128 * LDT];
    __shared__ short bs[3][128 * LDT];
    __shared__ float bsrc[32 * 128];

    const int tid = threadIdx.x;
    const int lane = tid & 63;
    const int wid = tid >> 6;
    const int wr = (wid >> 1) * 64;
    const int wc = (wid & 1) * 64;
    const int l15 = lane & 15;
    const int lk8 = (lane >> 4) * 8;
    const int bm = blockIdx.y * 128;
    const int bn = blockIdx.x * 128;

    const int tn = tid & 127;
    const int tkh = (tid >> 7) * 16;

    f32x4 accM[4][4];
    f32x4 accR[4][4];
#pragma unroll
    for (int i = 0; i < 4; ++i)
#pragma unroll
        for (int j = 0; j < 4; ++j) {
            accM[i][j] = (f32x4){0.f, 0.f, 0.f, 0.f};
            accR[i][j] = (f32x4){0.f, 0.f, 0.f, 0.f};
        }

    for (int k0 = 0; k0 < IDIM; k0 += 32) {
        __syncthreads();

#pragma unroll
        for (int pass = 0; pass < 4; ++pass) {
            int idx = pass * 256 + tid;
            int m = idx >> 3;
            int kf = (idx & 7) << 2;
            float4 v = *(const float4*)(A + (size_t)(bm + m) * IDIM + k0 + kf);
            short s0[4], s1[4], s2[4];
            split3(v.x, s0[0], s1[0], s2[0]);
            split3(v.y, s0[1], s1[1], s2[1]);
            split3(v.z, s0[2], s1[2], s2[2]);
            split3(v.w, s0[3], s1[3], s2[3]);
            int off = m * LDT + kf;
            *(short4*)&as[0][off] = make_short4(s0[0], s0[1], s0[2], s0[3]);
            *(short4*)&as[1][off] = make_short4(s1[0], s1[1], s1[2], s1[3]);
            *(short4*)&as[2][off] = make_short4(s2[0], s2[1], s2[2], s2[3]);
        }
#pragma unroll
        for (int pass = 0; pass < 4; ++pass) {
            int idx = pass * 256 + tid;
            int k = idx >> 5;
            int nf = (idx & 31) << 2;
            float4 v = *(const float4*)(B + (size_t)(k0 + k) * DDIM + bn + nf);
            *(float4*)&bsrc[k * 128 + nf] = v;
        }
        __syncthreads();

#pragma unroll
        for (int q = 0; q < 4; ++q) {
            int kq = tkh + q * 4;
            short s0[4], s1[4], s2[4];
#pragma unroll
            for (int e = 0; e < 4; ++e) {
                float f = bsrc[(kq + e) * 128 + tn];
                split3(f, s0[e], s1[e], s2[e]);
            }
            int off = tn * LDT + kq;
            *(short4*)&bs[0][off] = make_short4(s0[0], s0[1], s0[2], s0[3]);
            *(short4*)&bs[1][off] = make_short4(s1[0], s1[1], s1[2], s1[3]);
            *(short4*)&bs[2][off] = make_short4(s2[0], s2[1], s2[2], s2[3]);
        }
        __syncthreads();

        bf16x8 af[3][4];
#pragma unroll
        for (int p = 0; p < 3; ++p)
#pragma unroll
            for (int mi = 0; mi < 4; ++mi)
                af[p][mi] = *(const bf16x8*)&as[p][(wr + mi * 16 + l15) * LDT + lk8];

#pragma unroll
        for (int q = 0; q < 3; ++q) {
            bf16x8 bf[4];
#pragma unroll
            for (int ni = 0; ni < 4; ++ni)
                bf[ni] = *(const bf16x8*)&bs[q][(wc + ni * 16 + l15) * LDT + lk8];
#pragma unroll
            for (int p = 0; p < 3; ++p) {
                if (p + q > 2) continue;
                if (p == 0 && q == 0) {
#pragma unroll
                    for (int mi = 0; mi < 4; ++mi)
#pragma unroll
                        for (int ni = 0; ni < 4; ++ni)
                            accM[mi][ni] = __builtin_amdgcn_mfma_f32_16x16x32_bf16(
                                af[0][mi], bf[ni], accM[mi][ni], 0, 0, 0);
                } else {
#pragma unroll
                    for (int mi = 0; mi < 4; ++mi)
#pragma unroll
                        for (int ni = 0; ni < 4; ++ni)
                            accR[mi][ni] = __builtin_amdgcn_mfma_f32_16x16x32_bf16(
                                af[p][mi], bf[ni], accR[mi][ni], 0, 0, 0);
                }
            }
        }
    }

    const int rsub = (lane >> 4) * 4;
#pragma unroll
    for (int mi = 0; mi < 4; ++mi) {
        int row0 = bm + wr + mi * 16 + rsub;
#pragma unroll
        for (int ni = 0; ni < 4; ++ni) {
            int col = bn + wc + ni * 16 + l15;
            float bb = bias[col];
#pragma unroll
            for (int r = 0; r < 4; ++r) {
                float s = accR[mi][ni][r] + accM[mi][ni][r];
                C[(size_t)(row0 + r) * DDIM + col] = fmaxf(s + bb, 0.f);
            }
        }
    }
}

// ---- GEMM3: h3 = relu(flat @ W3 + b3), 2-term split (value-only) -----------
// A: [M][DDIM] fp32, B: [DDIM][IDIM] fp32, C: [M][IDIM] fp32.
// Products a0b0 (accM) + a0b1 + a1b0 (accR); dropped a1b1 ~ 2^-16 relative.
__global__ __launch_bounds__(256, 2)
void gemm3_split(const float* __restrict__ A, const float* __restrict__ B,
                 const float* __restrict__ bias, float* __restrict__ C)
{
    __shared__ short as[2][128 * LDT];
    __shared__ short bs[2][128 * LDT];
    __shared__ float bsrc[32 * 128];

    const int tid = threadIdx.x;
    const int lane = tid & 63;
    const int wid = tid >> 6;
    const int wr = (wid >> 1) * 64;
    const int wc = (wid & 1) * 64;
    const int l15 = lane & 15;
    const int lk8 = (lane >> 4) * 8;
    const int bm = blockIdx.y * 128;
    const int bn = blockIdx.x * 128;

    const int tn = tid & 127;
    const int tkh = (tid >> 7) * 16;

    f32x4 accM[4][4];
    f32x4 accR[4][4];
#pragma unroll
    for (int i = 0; i < 4; ++i)
#pragma unroll
        for (int j = 0; j < 4; ++j) {
            accM[i][j] = (f32x4){0.f, 0.f, 0.f, 0.f};
            accR[i][j] = (f32x4){0.f, 0.f, 0.f, 0.f};
        }

    for (int k0 = 0; k0 < DDIM; k0 += 32) {
        __syncthreads();

        // stage A: 128m x 32k fp32 -> split2 -> as[0..1]
#pragma unroll
        for (int pass = 0; pass < 4; ++pass) {
            int idx = pass * 256 + tid;
            int m = idx >> 3;
            int kf = (idx & 7) << 2;
            float4 v = *(const float4*)(A + (size_t)(bm + m) * DDIM + k0 + kf);
            short s0[4], s1[4];
            split2(v.x, s0[0], s1[0]);
            split2(v.y, s0[1], s1[1]);
            split2(v.z, s0[2], s1[2]);
            split2(v.w, s0[3], s1[3]);
            int off = m * LDT + kf;
            *(short4*)&as[0][off] = make_short4(s0[0], s0[1], s0[2], s0[3]);
            *(short4*)&as[1][off] = make_short4(s1[0], s1[1], s1[2], s1[3]);
        }
        // stage B pass 1: 32k x 128n fp32, coalesced -> bsrc
#pragma unroll
        for (int pass = 0; pass < 4; ++pass) {
            int idx = pass * 256 + tid;
            int k = idx >> 5;
            int nf = (idx & 31) << 2;
            float4 v = *(const float4*)(B + (size_t)(k0 + k) * IDIM + bn + nf);
            *(float4*)&bsrc[k * 128 + nf] = v;
        }
        __syncthreads();

        // stage B pass 2: transpose + split2 -> bs[0..1]
#pragma unroll
        for (int q = 0; q < 4; ++q) {
            int kq = tkh + q * 4;
            short s0[4], s1[4];
#pragma unroll
            for (int e = 0; e < 4; ++e) {
                float f = bsrc[(kq + e) * 128 + tn];
                split2(f, s0[e], s1[e]);
            }
            int off = tn * LDT + kq;
            *(short4*)&bs[0][off] = make_short4(s0[0], s0[1], s0[2], s0[3]);
            *(short4*)&bs[1][off] = make_short4(s1[0], s1[1], s1[2], s1[3]);
        }
        __syncthreads();

        bf16x8 af[2][4];
#pragma unroll
        for (int p = 0; p < 2; ++p)
#pragma unroll
            for (int mi = 0; mi < 4; ++mi)
                af[p][mi] = *(const bf16x8*)&as[p][(wr + mi * 16 + l15) * LDT + lk8];

#pragma unroll
        for (int q = 0; q < 2; ++q) {
            bf16x8 bf[4];
#pragma unroll
            for (int ni = 0; ni < 4; ++ni)
                bf[ni] = *(const bf16x8*)&bs[q][(wc + ni * 16 + l15) * LDT + lk8];
#pragma unroll
            for (int p = 0; p < 2; ++p) {
                if (p + q > 1) continue;
                if (p == 0 && q == 0) {
#pragma unroll
                    for (int mi = 0; mi < 4; ++mi)
#pragma unroll
                        for (int ni = 0; ni < 4; ++ni)
                            accM[mi][ni] = __builtin_amdgcn_mfma_f32_16x16x32_bf16(
                                af[0][mi], bf[ni], accM[mi][ni], 0, 0, 0);
                } else {
#pragma unroll
                    for (int mi = 0; mi < 4; ++mi)
#pragma unroll
                        for (int ni = 0; ni < 4; ++ni)
                            accR[mi][ni] = __builtin_amdgcn_mfma_f32_16x16x32_bf16(
                                af[p][mi], bf[ni], accR[mi][ni], 0, 0, 0);
                }
            }
        }
    }

    const int rsub = (lane >> 4) * 4;
#pragma unroll
    for (int mi = 0; mi < 4; ++mi) {
        int row0 = bm + wr + mi * 16 + rsub;
#pragma unroll
        for (int ni = 0; ni < 4; ++ni) {
            int col = bn + wc + ni * 16 + l15;
            float bb = bias[col];
#pragma unroll
            for (int r = 0; r < 4; ++r) {
                float s = accR[mi][ni][r] + accM[mi][ni][r];
                C[(size_t)(row0 + r) * IDIM + col] = fmaxf(s + bb, 0.f);
            }
        }
    }
}

// ---- k-winner (exact top-512, radix on fp32 bits, jax leftmost ties) -------
__global__ __launch_bounds__(256)
void kwinner_stripes(float* h2, const float* bscores)
{
    const int row = blockIdx.x;
    const int tid = threadIdx.x;
    float* rowp = h2 + (size_t)row * DDIM;

    __shared__ float  mv[DDIM];
    __shared__ int    ired[256];
    __shared__ double dred[256];
    __shared__ int    warr[4];
    __shared__ double ssum[128];
    __shared__ float  smk[128];

#pragma unroll
    for (int i = 0; i < 32; ++i) {
        int j = tid + i * 256;
        mv[j] = expf(0.0f - bscores[j]) * rowp[j];   // BETA=1, GAMMA=0
    }
    __syncthreads();

    unsigned t = 0;
    for (int bit = 30; bit >= 0; --bit) {
        unsigned cand = t | (1u << bit);
        int cnt = 0;
#pragma unroll
        for (int i = 0; i < 32; ++i)
            cnt += (__float_as_uint(mv[tid + i * 256]) >= cand) ? 1 : 0;
        for (int off = 32; off; off >>= 1) cnt += __shfl_down(cnt, off);
        if ((tid & 63) == 0) warr[tid >> 6] = cnt;
        __syncthreads();
        int tot = warr[0] + warr[1] + warr[2] + warr[3];
        __syncthreads();
        if (tot >= KNEUR) t = cand;
    }
    {
        int cnt = 0;
#pragma unroll
        for (int i = 0; i < 32; ++i)
            cnt += (__float_as_uint(mv[tid + i * 256]) > t) ? 1 : 0;
        for (int off = 32; off; off >>= 1) cnt += __shfl_down(cnt, off);
        if ((tid & 63) == 0) warr[tid >> 6] = cnt;
        __syncthreads();
    }
    const int need_eq = KNEUR - (warr[0] + warr[1] + warr[2] + warr[3]);
    __syncthreads();

    const int base = tid * 32;
    int myeq = 0;
#pragma unroll
    for (int i = 0; i < 32; ++i)
        myeq += (__float_as_uint(mv[base + i]) == t) ? 1 : 0;
    int val = myeq;
    ired[tid] = val;
    __syncthreads();
    for (int s = 1; s < 256; s <<= 1) {
        int add = (tid >= s) ? ired[tid - s] : 0;
        __syncthreads();
        val += add;
        ired[tid] = val;
        __syncthreads();
    }
    const int before = val - myeq;

    double partial = 0.0;
    int eqseen = 0;
#pragma unroll
    for (int i = 0; i < 32; ++i) {
        int j = base + i;
        float m = mv[j];
        unsigned u = __float_as_uint(m);
        bool sel = (u > t) || (u == t && (before + eqseen) < need_eq);
        if (u == t) ++eqseen;
        float code = sel ? m * rowp[j] : 0.f;
        mv[j] = code;
        partial += (double)code;
    }
    dred[tid] = partial;
    __syncthreads();
    if (tid < 128) ssum[tid] = dred[2 * tid] + dred[2 * tid + 1];
    __syncthreads();

    if (tid < 128) {
        double v = ssum[tid];
        int rank = 0;
        for (int j = 0; j < 128; ++j) {
            double w = ssum[j];
            rank += (w > v) ? 1 : 0;
            rank += (w == v && j < tid) ? 1 : 0;
        }
        smk[tid] = (rank < KSTR) ? 1.f : 0.f;
    }
    __syncthreads();

#pragma unroll
    for (int i = 0; i < 32; ++i) {
        int j = tid + i * 256;
        rowp[j] = mv[j] * smk[j >> 6];
    }
}

extern "C" void kernel_launch(void* const* d_in, const int* in_sizes, int n_in,
                              void* d_out, int out_size, void* d_ws, size_t ws_size,
                              hipStream_t stream)
{
    float* out = (float*)d_out;
    const unsigned long long on = (unsigned long long)out_size;

    if (n_in != 10) {
        Net_49976239456390_kernel<<<1024, 256, 0, stream>>>(out, on, 55.f);
        return;
    }
    if (in_sizes[0] != BDIM * XDIM || in_sizes[3] != IDIM * DDIM || in_sizes[9] != DDIM) {
        Net_49976239456390_kernel<<<1024, 256, 0, stream>>>(out, on, 66.f);
        return;
    }

    const size_t per_row = (size_t)(IDIM + DDIM) * 4;
    int R = 0;
    for (int cand = BDIM; cand >= 128; cand >>= 1)
        if ((size_t)cand * per_row <= ws_size) { R = cand; break; }
    if (R == 0) {
        Net_49976239456390_kernel<<<1024, 256, 0, stream>>>(out, on, 99.f);
        return;
    }

    Net_49976239456390_kernel<<<1024, 256, 0, stream>>>(out, on, 7.f);

    const float* x   = (const float*)d_in[0];
    const float* W1  = (const float*)d_in[1];
    const float* b1  = (const float*)d_in[2];
    const float* W2  = (const float*)d_in[3];
    const float* b2  = (const float*)d_in[4];
    const float* W3  = (const float*)d_in[5];
    const float* b3  = (const float*)d_in[6];
    const float* W4  = (const float*)d_in[7];
    const float* b4  = (const float*)d_in[8];
    const float* bsc = (const float*)d_in[9];

    float* h1 = (float*)d_ws;
    float* h2 = h1 + (size_t)R * IDIM;

    dim3 blk(256);
    for (int cs = 0; cs < BDIM; cs += R) {
        const float* xC = x + (size_t)cs * XDIM;
        float* outC = out + (size_t)cs * XDIM;

        gemm_relu<<<dim3(IDIM / 128, R / 128), blk, 0, stream>>>(xC, W1, b1, h1, IDIM, XDIM);
        gemm2_split<<<dim3(DDIM / 128, R / 128), blk, 0, stream>>>(h1, W2, b2, h2);
        kwinner_stripes<<<dim3(R), blk, 0, stream>>>(h2, bsc);
        gemm3_split<<<dim3(IDIM / 128, R / 128), blk, 0, stream>>>(h2, W3, b3, h1);
        gemm_relu<<<dim3((XDIM + 127) / 128, R / 128), blk, 0, stream>>>(h1, W4, b4, outC, XDIM, IDIM);
    }
}